// Round 16
// baseline (990.034 us; speedup 1.0000x reference)
//
#include <hip/hip_runtime.h>

#define NB 64
#define EDGES 1048576   /* 64*1024*16 */
#define NTOT  65536

struct __align__(8) CsrE { int s; float w; };

using bf16x8 = __attribute__((ext_vector_type(8))) short;   // 8 bf16 (4 VGPRs)
using f32x4  = __attribute__((ext_vector_type(4))) float;   // 4 fp32 acc

__global__ void k_zerof(float* __restrict__ p, int n){
  int i=blockIdx.x*256+threadIdx.x; if(i<n) p[i]=0.f;
}

// ---------------- bf16x3 split helpers (RNE) ----------------
__device__ inline void split1(float x, unsigned &hi16, unsigned &lo16){
  unsigned b=__float_as_uint(x);
  unsigned h=(b+0x7FFFu+((b>>16)&1u))&0xFFFF0000u;
  float lf=x-__uint_as_float(h);
  unsigned lb=__float_as_uint(lf);
  hi16=h>>16;
  lo16=(lb+0x7FFFu+((lb>>16)&1u))>>16;
}

__device__ inline void split8(const float4&u, const float4&v, bf16x8&hi, bf16x8&lo){
  float e[8]={u.x,u.y,u.z,u.w,v.x,v.y,v.z,v.w};
  #pragma unroll
  for(int j=0;j<8;++j){
    unsigned h16,l16; split1(e[j],h16,l16);
    hi[j]=(short)h16; lo[j]=(short)l16;
  }
}

// Merged launch: blocks [0,512) = CSR count (8 chunks x 64 graphs, XCD-pinned,
// LDS histogram of 2048 edges); blocks [512,536) = W prepack (3 matrices into
// MFMA B-fragment order, bf16 hi/lo). Pack block 0 also zeroes the per-graph
// tail counters (workspace is poisoned between calls).
// Pack layout (u32): off(q,c,hl,l,i) = (((q*8+c)*2+hl)*64+l)*4+i
//   B[k][n]: k = 32q + 8*(l>>4) + j, n = 16c + (l&15); elem j=2i(lo),2i+1(hi).
__global__ __launch_bounds__(256) void k_cntpack(const int* __restrict__ edst,
        const float* __restrict__ ew, int* __restrict__ chunkcnt, float* __restrict__ chunkw,
        const float* __restrict__ W1, const float* __restrict__ W2,
        const float* __restrict__ W3, unsigned* __restrict__ outp,
        int* __restrict__ gcnt){
  __shared__ int lc[1024];
  __shared__ float lw[1024];
  int b=blockIdx.x, tid=threadIdx.x;
  if(b<512){
    int xcd=b&7, slot=b>>3;
    int graph=xcd*8+(slot&7), chunk=slot>>3;     // chunk in [0,8)
    int e0=graph*16384+chunk*2048;
    for(int t=tid;t<1024;t+=256){ lc[t]=0; lw[t]=0.f; }
    __syncthreads();
    for(int e=e0+tid; e<e0+2048; e+=256){
      int dl=edst[e]&1023;
      atomicAdd(&lc[dl],1);
      atomicAdd(&lw[dl],ew[e]);
    }
    __syncthreads();
    for(int t=tid;t<1024;t+=256){
      chunkcnt[chunk*65536+graph*1024+t]=lc[t];
      chunkw  [chunk*65536+graph*1024+t]=lw[t];
    }
  } else {
    int wb=b-512, m=wb>>3;
    if(wb==0 && tid<64) gcnt[tid]=0;
    const float* W = (m==0)?W1:((m==1)?W2:W3);
    unsigned* o = outp + m*16384;
    for(int t=(wb&7)*256+tid; t<8192; t+=2048){
      int i=t&3, l=(t>>2)&63, c=(t>>8)&7, q=(t>>11)&3;
      int col=c*16+(l&15);
      int k0=q*32+((l>>4)<<3)+i*2;
      float x0=W[k0*128+col], x1=W[(k0+1)*128+col];
      unsigned h0,l0,h1,l1;
      split1(x0,h0,l0); split1(x1,h1,l1);
      int base=((q*8+c)*2)*256;           // u32 index of (q,c,hl=0)
      o[base + l*4 + i]       = (h1<<16)|h0;
      o[base + 256 + l*4 + i] = (l1<<16)|l0;
    }
  }
}

// Merged launch 2: blocks [0,512) = stage-1 MFMA matmul (128 rows each);
// blocks [512,1024) = CSR scatter w/ fused per-graph scan.
// LDS = 16 KB (W staged per q-chunk, 4 stages).
__global__ __launch_bounds__(256) void k_mm1scat(const float* __restrict__ X,
        const unsigned* __restrict__ Wpk,
        const int* __restrict__ esrc, const int* __restrict__ edst,
        const float* __restrict__ ew, const int* __restrict__ chunkcnt,
        const float* __restrict__ chunkw, int* __restrict__ rowptr,
        float* __restrict__ dinv1, CsrE* __restrict__ csr,
        float* __restrict__ Y){
  __shared__ __align__(16) unsigned Wl[4096];   // 16 KB (mm role); scatter aliases
  int b=blockIdx.x;
  if(b<512){
    const int RPB=128;
    int row0b=b*RPB;
    const int wave=threadIdx.x>>6, lane=threadIdx.x&63;
    const int row0=row0b+wave*32;
    const int lrow=lane&15, lko=(lane>>4)<<3;
    int orow[2];
    #pragma unroll
    for(int s=0;s<2;++s) orow[s]=row0+s*16+lrow;
    const f32x4 vzero={0.f,0.f,0.f,0.f};
    f32x4 acc[2][8];
    #pragma unroll
    for(int s=0;s<2;++s){
      #pragma unroll
      for(int c=0;c<8;++c) acc[s][c]=vzero;
    }
    const char* wb=(const char*)Wl + lane*16;
    float4 u[2],v[2];
    #pragma unroll
    for(int s=0;s<2;++s){
      const float* xp=X+(size_t)orow[s]*128+lko;
      u[s]=*(const float4*)xp; v[s]=*(const float4*)(xp+4);
    }
    #pragma unroll
    for(int q=0;q<4;++q){
      if(q) __syncthreads();             // all waves done reading chunk q-1
      for(int t=threadIdx.x;t<1024;t+=256)
        ((uint4*)Wl)[t]=((const uint4*)Wpk)[q*1024+t];
      __syncthreads();
      float4 un[2],vn[2];
      if(q<3){
        #pragma unroll
        for(int s=0;s<2;++s){
          const float* xp=X+(size_t)orow[s]*128+(q+1)*32+lko;
          un[s]=*(const float4*)xp; vn[s]=*(const float4*)(xp+4);
        }
      }
      bf16x8 Ah[2],Al[2];
      #pragma unroll
      for(int s=0;s<2;++s) split8(u[s],v[s],Ah[s],Al[s]);
      #pragma unroll
      for(int c=0;c<8;++c){
        const bf16x8 bh=*(const bf16x8*)(wb + c*2048);
        const bf16x8 bl=*(const bf16x8*)(wb + c*2048 + 1024);
        #pragma unroll
        for(int s=0;s<2;++s){
          acc[s][c]=__builtin_amdgcn_mfma_f32_16x16x32_bf16(Ah[s],bh,acc[s][c],0,0,0);
          acc[s][c]=__builtin_amdgcn_mfma_f32_16x16x32_bf16(Al[s],bh,acc[s][c],0,0,0);
          acc[s][c]=__builtin_amdgcn_mfma_f32_16x16x32_bf16(Ah[s],bl,acc[s][c],0,0,0);
        }
      }
      if(q<3){
        #pragma unroll
        for(int s=0;s<2;++s){ u[s]=un[s]; v[s]=vn[s]; }
      }
    }
    const int dcol=lane&15, dr0=(lane>>4)<<2;
    #pragma unroll
    for(int s=0;s<2;++s){
      #pragma unroll
      for(int c=0;c<8;++c){
        #pragma unroll
        for(int r=0;r<4;++r){
          Y[(size_t)(row0+s*16+dr0+r)*128 + c*16 + dcol]=acc[s][c][r];
        }
      }
    }
  } else {
    int* lc=(int*)Wl;            // [0,1024) fill counters
    int* wsum=(int*)Wl+1024;     // wave partials
    int sb=b-512, i=threadIdx.x;
    int lane=i&63, w=i>>6;
    int xcd=sb&7, slot=sb>>3;
    int graph=xcd*8+(slot&7), chunk=slot>>3;    // chunk in [0,8)
    int n0=4*i, o0=graph*1024+n0;
    int ck[4][8], csum[4];
    int tot=0;
    #pragma unroll
    for(int j=0;j<4;++j){
      int c=0;
      #pragma unroll
      for(int k=0;k<8;++k){ int t=chunkcnt[k*65536+o0+j]; ck[j][k]=t; c+=t; }
      csum[j]=c; tot+=c;
    }
    int v=tot;
    #pragma unroll
    for(int off=1;off<64;off<<=1){ int t=__shfl_up(v,off,64); if(lane>=off) v+=t; }
    if(lane==63) wsum[w]=v;
    __syncthreads();
    int base=0;
    for(int k=0;k<w;++k) base+=wsum[k];
    int texcl=base+v-tot;
    int run=texcl;
    #pragma unroll
    for(int j=0;j<4;++j){
      int r0=graph*16384+run;
      if(chunk==0){
        rowptr[o0+j]=r0;
        float wsv=0.f;
        #pragma unroll
        for(int k=0;k<8;++k) wsv+=chunkw[k*65536+o0+j];
        dinv1[o0+j]=rsqrtf(wsv+1.0f);
      }
      int myfill=r0;
      #pragma unroll
      for(int k=0;k<8;++k) if(k<chunk) myfill+=ck[j][k];
      lc[n0+j]=myfill;
      run+=csum[j];
    }
    if(graph==63 && chunk==0 && i==255) rowptr[65536]=EDGES;
    __syncthreads();
    int e0=graph*16384+chunk*2048;
    for(int e=e0+i; e<e0+2048; e+=256){
      int dl=edst[e]&1023;
      int pos=atomicAdd(&lc[dl],1);
      CsrE ce; ce.s=esrc[e]; ce.w=ew[e];
      csr[pos]=ce;
    }
  }
}

// Y[R x 128] = act(A)[R x 128] @ W[128 x 128] via mfma_f32_16x16x32_bf16.
// LDS = 16 KB (per-q-chunk W staging, 4 stages). First MMB blocks do the
// matmul; extra blocks run a fused epilogue:
//   EPI=2: degrow2. EPI=3: compose (inv12,map12) + degrow3.
template<bool G, int S, int EPI, int MMB>
__global__ __launch_bounds__(256) void mm_mfma(const float* __restrict__ X,
        const unsigned* __restrict__ Wpk, const int* __restrict__ selold,
        const float* __restrict__ score, float* __restrict__ Y, int gshift,
        const int* __restrict__ inv1, const int* __restrict__ sel1,
        const int* __restrict__ inv2, const int* __restrict__ sel2,
        int* __restrict__ inv12, int* __restrict__ map12,
        const int* __restrict__ rowptr, const CsrE* __restrict__ csr,
        float* __restrict__ dinv_out){
  __shared__ __align__(16) unsigned Wl[4096];   // 16 KB
  int b=blockIdx.x;
  if(b<MMB){
    const int RPB = 64*S;
    int row0b;
    if(G){
      int xcd=b&7, slot=b>>3, bpg=1<<gshift;
      int graph=xcd*8+(slot>>gshift), idx=slot&(bpg-1);
      row0b = graph*(bpg*RPB) + idx*RPB;
    } else row0b = b*RPB;
    const int wave=threadIdx.x>>6, lane=threadIdx.x&63;
    const int row0 = row0b + wave*(16*S);
    const int lrow=lane&15, lko=(lane>>4)<<3;
    int orow[S]; float scr[S];
    #pragma unroll
    for(int s=0;s<S;++s){
      int rr=row0+s*16+lrow;
      orow[s]=G?selold[rr]:rr;
      scr[s]=G?score[orow[s]]:1.f;
    }
    const f32x4 vzero={0.f,0.f,0.f,0.f};
    f32x4 acc[S][8];
    #pragma unroll
    for(int s=0;s<S;++s){
      #pragma unroll
      for(int c=0;c<8;++c) acc[s][c]=vzero;
    }
    const char* wb=(const char*)Wl + lane*16;
    float4 u[S],v[S];
    #pragma unroll
    for(int s=0;s<S;++s){
      const float* xp=X+(size_t)orow[s]*128+lko;
      u[s]=*(const float4*)xp; v[s]=*(const float4*)(xp+4);
    }
    #pragma unroll
    for(int q=0;q<4;++q){
      if(q) __syncthreads();             // all waves done reading chunk q-1
      for(int t=threadIdx.x;t<1024;t+=256)
        ((uint4*)Wl)[t]=((const uint4*)Wpk)[q*1024+t];
      __syncthreads();
      float4 un[S],vn[S];
      if(q<3){
        #pragma unroll
        for(int s=0;s<S;++s){
          const float* xp=X+(size_t)orow[s]*128+(q+1)*32+lko;
          un[s]=*(const float4*)xp; vn[s]=*(const float4*)(xp+4);
        }
      }
      bf16x8 Ah[S],Al[S];
      #pragma unroll
      for(int s=0;s<S;++s){
        if(G){
          u[s].x=fmaxf(u[s].x*scr[s],0.f); u[s].y=fmaxf(u[s].y*scr[s],0.f);
          u[s].z=fmaxf(u[s].z*scr[s],0.f); u[s].w=fmaxf(u[s].w*scr[s],0.f);
          v[s].x=fmaxf(v[s].x*scr[s],0.f); v[s].y=fmaxf(v[s].y*scr[s],0.f);
          v[s].z=fmaxf(v[s].z*scr[s],0.f); v[s].w=fmaxf(v[s].w*scr[s],0.f);
        }
        split8(u[s],v[s],Ah[s],Al[s]);
      }
      #pragma unroll
      for(int c=0;c<8;++c){
        const bf16x8 bh=*(const bf16x8*)(wb + c*2048);
        const bf16x8 bl=*(const bf16x8*)(wb + c*2048 + 1024);
        #pragma unroll
        for(int s=0;s<S;++s){
          acc[s][c]=__builtin_amdgcn_mfma_f32_16x16x32_bf16(Ah[s],bh,acc[s][c],0,0,0);
          acc[s][c]=__builtin_amdgcn_mfma_f32_16x16x32_bf16(Al[s],bh,acc[s][c],0,0,0);
          acc[s][c]=__builtin_amdgcn_mfma_f32_16x16x32_bf16(Ah[s],bl,acc[s][c],0,0,0);
        }
      }
      if(q<3){
        #pragma unroll
        for(int s=0;s<S;++s){ u[s]=un[s]; v[s]=vn[s]; }
      }
    }
    const int dcol=lane&15, dr0=(lane>>4)<<2;
    #pragma unroll
    for(int s=0;s<S;++s){
      #pragma unroll
      for(int c=0;c<8;++c){
        #pragma unroll
        for(int r=0;r<4;++r){
          Y[(size_t)(row0+s*16+dr0+r)*128 + c*16 + dcol]=acc[s][c][r];
        }
      }
    }
    return;
  }
  if(EPI==2){
    int v=(b-MMB)*256+threadIdx.x;        // [0, 32768)
    int d0=sel1[v];
    int rs=rowptr[d0], re=rowptr[d0+1];
    float s0=0.f,s1=0.f,s2=0.f,s3=0.f;
    int e=rs;
    for(; e+4<=re; e+=4){
      CsrE e0=csr[e], e1=csr[e+1], e2=csr[e+2], e3=csr[e+3];
      if(inv1[e0.s]>=0) s0+=e0.w;
      if(inv1[e1.s]>=0) s1+=e1.w;
      if(inv1[e2.s]>=0) s2+=e2.w;
      if(inv1[e3.s]>=0) s3+=e3.w;
    }
    for(; e<re; ++e){
      CsrE en=csr[e];
      if(inv1[en.s]>=0) s0+=en.w;
    }
    dinv_out[v]=rsqrtf((s0+s1)+(s2+s3)+1.0f);
  }
  if(EPI==3){
    int g=b-MMB, i=threadIdx.x;
    for(int t=i; t<1024; t+=256){
      int v0=g*1024+t;
      int q=inv1[v0];
      inv12[v0]=(q>=0)?inv2[q]:-1;
    }
    int v=g*256+i;
    map12[v]=sel1[sel2[v]];
    __syncthreads();   // inv12/map12 (this graph) visible in-block
    int d0=map12[v];
    int rs=rowptr[d0], re=rowptr[d0+1];
    float s0=0.f,s1=0.f,s2=0.f,s3=0.f;
    int e=rs;
    for(; e+4<=re; e+=4){
      CsrE e0=csr[e], e1=csr[e+1], e2=csr[e+2], e3=csr[e+3];
      if(inv12[e0.s]>=0) s0+=e0.w;
      if(inv12[e1.s]>=0) s1+=e1.w;
      if(inv12[e2.s]>=0) s2+=e2.w;
      if(inv12[e3.s]>=0) s3+=e3.w;
    }
    for(; e<re; ++e){
      CsrE en=csr[e];
      if(inv12[en.s]>=0) s0+=en.w;
    }
    dinv_out[v]=rsqrtf((s0+s1)+(s2+s3)+1.0f);
  }
}

// 2 nodes per wave (half-wave of 32 lanes each). XCD-swizzled. Branch-free
// 4-edge groups via width-32 shfl broadcast. Fused score (width-32 reduce).
// TAIL=true (stage 1 only): the LAST finisher block of each graph (device
// atomic gcnt hits (1<<gshift)-1 = 127) runs topk1 for that graph in-place:
// 256-thr x 4-key radix select, element order j*256+i => tie-ranks bit-
// identical to the 1024-thread k_topk. __threadfence release/acquire orders
// the score hand-off; no waiting => deadlock-free.
template<bool F, bool TAIL>
__global__ __launch_bounds__(256) void k_gather(const float* __restrict__ xw, const CsrE* __restrict__ csr,
        const int* __restrict__ rowptr, const int* __restrict__ map, const int* __restrict__ inv,
        const float* __restrict__ dinvv, const float* __restrict__ bias, const float* __restrict__ p,
        float* __restrict__ h, float* __restrict__ score, int gshift, int ns,
        int* __restrict__ gcnt, int* __restrict__ invO, int* __restrict__ selO){
  __shared__ unsigned tl_hist[256];
  __shared__ int tl_wsum[4];
  __shared__ int tl_ws2[16];
  __shared__ int tl_c, tl_r, tl_last;
  int wv=threadIdx.x>>6, half=(threadIdx.x>>5)&1, hl=threadIdx.x&31;
  int b=blockIdx.x, xcd=b&7, slot=b>>3, bpg=1<<gshift;
  int graph=xcd*8+(slot>>gshift), idx=slot&(bpg-1);
  int v = graph*(bpg<<3) + (idx<<3) + wv*2 + half;   // 8 nodes per block
  if(v<ns){
    int d0 = F? map[v] : v;
    float dv=dinvv[v];
    int rs=rowptr[d0], re=rowptr[d0+1];
    const int f4=hl*4;
    float4 accA={0.f,0.f,0.f,0.f}, accB={0.f,0.f,0.f,0.f};
    for(int base=rs; base<re; base+=32){
      int len=re-base; if(len>32) len=32;
      int sidx=0; float cf=0.f;
      if(hl<len){
        CsrE en=csr[base+hl];
        int s=en.s; bool live=true;
        if(F){ int t=inv[s]; live=(t>=0); s=live?t:0; }
        if(live){ sidx=s; cf=dinvv[s]*en.w; }
      }
      int len4=(len+3)&~3;
      for(int j=0;j<len4;j+=4){
        float c0=__shfl(cf,j,32),   c1=__shfl(cf,j+1,32);
        float c2=__shfl(cf,j+2,32), c3=__shfl(cf,j+3,32);
        int   s0=__shfl(sidx,j,32),   s1=__shfl(sidx,j+1,32);
        int   s2=__shfl(sidx,j+2,32), s3=__shfl(sidx,j+3,32);
        const float4 x0=*(const float4*)&xw[(size_t)s0*128+f4];
        const float4 x1=*(const float4*)&xw[(size_t)s1*128+f4];
        const float4 x2=*(const float4*)&xw[(size_t)s2*128+f4];
        const float4 x3=*(const float4*)&xw[(size_t)s3*128+f4];
        accA.x+=c0*x0.x; accA.y+=c0*x0.y; accA.z+=c0*x0.z; accA.w+=c0*x0.w;
        accB.x+=c1*x1.x; accB.y+=c1*x1.y; accB.z+=c1*x1.z; accB.w+=c1*x1.w;
        accA.x+=c2*x2.x; accA.y+=c2*x2.y; accA.z+=c2*x2.z; accA.w+=c2*x2.w;
        accB.x+=c3*x3.x; accB.y+=c3*x3.y; accB.z+=c3*x3.z; accB.w+=c3*x3.w;
      }
    }
    float4 acc; acc.x=accA.x+accB.x; acc.y=accA.y+accB.y;
    acc.z=accA.z+accB.z; acc.w=accA.w+accB.w;
    const float4 xv=*(const float4*)&xw[(size_t)v*128+f4];
    const float4 bv=*(const float4*)&bias[f4];
    float d2=dv*dv;
    float4 hv;
    hv.x=acc.x*dv + d2*xv.x + bv.x;
    hv.y=acc.y*dv + d2*xv.y + bv.y;
    hv.z=acc.z*dv + d2*xv.z + bv.z;
    hv.w=acc.w*dv + d2*xv.w + bv.w;
    *(float4*)&h[(size_t)v*128+f4]=hv;
    const float4 pv=*(const float4*)&p[f4];
    float z=hv.x*pv.x+hv.y*pv.y+hv.z*pv.z+hv.w*pv.w;
    float pp=pv.x*pv.x+pv.y*pv.y+pv.z*pv.z+pv.w*pv.w;
    #pragma unroll
    for(int m=16;m>0;m>>=1){ z+=__shfl_xor(z,m,32); pp+=__shfl_xor(pp,m,32); }
    if(hl==0) score[v]=1.0f/(1.0f+expf(-z/sqrtf(pp)));
  }
  if(!TAIL) return;
  // ---------------- tail-fused topk1 (K=512 of N=1024 per graph) ----------------
  __threadfence();                        // release our score writes
  if(threadIdx.x==0)
    tl_last = (atomicAdd(&gcnt[graph],1) == (1<<gshift)-1);
  __syncthreads();
  if(!tl_last) return;
  __threadfence();                        // acquire other blocks' score writes
  int i=threadIdx.x, lane2=i&63, w2=i>>6;
  unsigned key[4]; int st[4]; unsigned byt[4];
  #pragma unroll
  for(int j=0;j<4;++j){ key[j]=__float_as_uint(score[graph*1024+j*256+i]); st[j]=1; }
  int R=512;
  for(int pass=0; pass<4; ++pass){
    int shift=24-pass*8;
    tl_hist[i]=0;
    __syncthreads();
    #pragma unroll
    for(int j=0;j<4;++j){
      byt[j]=(key[j]>>shift)&255u;
      if(st[j]==1) atomicAdd(&tl_hist[byt[j]],1u);
    }
    __syncthreads();
    unsigned hcnt=tl_hist[i], sfx=hcnt;
    #pragma unroll
    for(int off=1;off<64;off<<=1){
      unsigned t=__shfl_down(sfx,off,64);
      if(lane2+off<64) sfx+=t;
    }
    if(lane2==0) tl_wsum[w2]=(int)sfx;
    __syncthreads();
    int tot=0;
    for(int k=w2+1;k<4;++k) tot+=tl_wsum[k];
    int Si=(int)sfx+tot, A=Si-(int)hcnt;
    if(A<R && R<=Si){ tl_c=i; tl_r=R-A; }
    __syncthreads();
    int c=tl_c; R=tl_r;
    #pragma unroll
    for(int j=0;j<4;++j){
      if(st[j]==1){
        if((int)byt[j]>c) st[j]=2;
        else if((int)byt[j]<c) st[j]=0;
      }
    }
    __syncthreads();
  }
  int pre[4];
  #pragma unroll
  for(int j=0;j<4;++j){
    unsigned long long m=__ballot(st[j]==1);
    pre[j]=__popcll(m&((1ULL<<lane2)-1ULL));
    if(lane2==0) tl_ws2[j*4+w2]=__popcll(m);
  }
  __syncthreads();
  int sel[4];
  #pragma unroll
  for(int j=0;j<4;++j){
    int base=0;
    for(int jj=0;jj<j;++jj){ for(int k=0;k<4;++k) base+=tl_ws2[jj*4+k]; }
    for(int k=0;k<w2;++k) base+=tl_ws2[j*4+k];
    int tie=base+pre[j];
    sel[j]=(st[j]==2)||(st[j]==1 && tie<R);
  }
  __syncthreads();
  #pragma unroll
  for(int j=0;j<4;++j){
    unsigned long long m=__ballot(sel[j]);
    pre[j]=__popcll(m&((1ULL<<lane2)-1ULL));
    if(lane2==0) tl_ws2[j*4+w2]=__popcll(m);
  }
  __syncthreads();
  #pragma unroll
  for(int j=0;j<4;++j){
    int base=0;
    for(int jj=0;jj<j;++jj){ for(int k=0;k<4;++k) base+=tl_ws2[jj*4+k]; }
    for(int k=0;k<w2;++k) base+=tl_ws2[j*4+k];
    int ng=graph*512+base+pre[j];
    int gv=graph*1024+j*256+i;
    if(sel[j] && ng<NB*512){ invO[gv]=ng; selO[ng]=gv; }
    else invO[gv]=-1;
  }
}

// per-graph top-K via 4-pass MSB radix select. MODE 0: pure select.
// MODE 3: fused readout.
template<int N, int K, int MODE>
__global__ __launch_bounds__(N) void k_topk(const float* __restrict__ score,
        int* __restrict__ inv, int* __restrict__ selold,
        const float* __restrict__ h3, const float* __restrict__ Wo,
        const float* __restrict__ bo, float* __restrict__ outp){
  __shared__ unsigned hist[256];
  __shared__ int wsum[16];
  __shared__ int c_sh, r_sh;
  __shared__ float red[128];
  int g=blockIdx.x, i=threadIdx.x;
  int lane=i&63, w=i>>6;
  int gv=g*N+i;
  unsigned key=__float_as_uint(score[gv]);
  int st=1;              // 0=rejected, 1=alive, 2=selected
  int R=K;
  #pragma unroll
  for(int pass=0; pass<4; ++pass){
    int shift=24-pass*8;
    if(i<256) hist[i]=0;
    __syncthreads();
    unsigned byte=(key>>shift)&255u;
    if(st==1) atomicAdd(&hist[byte],1u);
    __syncthreads();
    unsigned hcnt=0, sfx=0;
    if(i<256){
      hcnt=hist[i]; sfx=hcnt;
      #pragma unroll
      for(int off=1;off<64;off<<=1){
        unsigned t=__shfl_down(sfx,off,64);
        if(lane+off<64) sfx+=t;
      }
      if(lane==0) wsum[w]=(int)sfx;
    }
    __syncthreads();
    if(i<256){
      int tot=0;
      for(int k=w+1;k<4;++k) tot+=wsum[k];
      int Si=(int)sfx+tot;
      int A=Si-(int)hcnt;
      if(A<R && R<=Si){ c_sh=i; r_sh=R-A; }
    }
    __syncthreads();
    int c=c_sh; R=r_sh;
    if(st==1){
      if((int)byte>c) st=2;
      else if((int)byte<c) st=0;
    }
    __syncthreads();
  }
  int alive=(st==1)?1:0;
  unsigned long long mA=__ballot(alive);
  int rA=__popcll(mA & ((1ULL<<lane)-1ULL));
  if(lane==0) wsum[w]=__popcll(mA);
  __syncthreads();
  int offA=0;
  for(int k=0;k<w;++k) offA+=wsum[k];
  int tie_rank=offA+rA;
  int sel=(st==2)||(st==1 && tie_rank<R);
  __syncthreads();
  unsigned long long mS=__ballot(sel);
  int rS=__popcll(mS & ((1ULL<<lane)-1ULL));
  if(lane==0) wsum[w]=__popcll(mS);
  __syncthreads();
  int offS=0;
  for(int k=0;k<w;++k) offS+=wsum[k];
  int ng=g*K+offS+rS;
  if(sel && ng<NB*K){ inv[gv]=ng; selold[ng]=gv; }
  else inv[gv]=-1;
  if(MODE==3){
    __syncthreads();   // selold (sel3) visible to the whole block
    int f=i;
    float mx=-3.4e38f, sm=0.f;
    if(f<128){
      for(int nd=0;nd<128;++nd){
        int old=selold[g*128+nd];
        float vv=fmaxf(h3[(size_t)old*128+f]*score[old],0.f);
        mx=fmaxf(mx,vv); sm+=vv;
      }
      float mean=sm*(1.0f/128.0f);
      outp[64+g*256+f]    =mx;
      outp[64+g*256+128+f]=mean;
      red[f]=mx*Wo[f]+mean*Wo[128+f];
    }
    __syncthreads();
    for(int off=64;off>0;off>>=1){
      if(f<off) red[f]+=red[f+off];
      __syncthreads();
    }
    if(f==0){ float z=red[0]+bo[0]; outp[g]=1.0f/(1.0f+expf(-z)); }
  }
}

extern "C" void kernel_launch(void* const* d_in, const int* in_sizes, int n_in,
                              void* d_out, int out_size, void* d_ws, size_t ws_size,
                              hipStream_t stream) {
  (void)in_sizes; (void)n_in;
  const float* x  = (const float*)d_in[0];
  const int*   ei = (const int*)d_in[1];
  const float* ew = (const float*)d_in[2];
  // d_in[3] = batch_index (unused; graphs are equal-sized)
  const float* W1=(const float*)d_in[4];  const float* b1=(const float*)d_in[5];  const float* p1=(const float*)d_in[6];
  const float* W2=(const float*)d_in[7];  const float* b2=(const float*)d_in[8];  const float* p2=(const float*)d_in[9];
  const float* W3=(const float*)d_in[10]; const float* b3=(const float*)d_in[11]; const float* p3=(const float*)d_in[12];
  const float* Wo=(const float*)d_in[13]; const float* bo=(const float*)d_in[14];
  float* out=(float*)d_out;

  // ---- workspace layout (~81 MiB) ----
  char* ws=(char*)d_ws;
  size_t cur=0;
  float* slot0=(float*)(ws+cur); cur+=33554432;          // xw1 / xw2 / xw3
  float* slot1=(float*)(ws+cur); cur+=33554432;          // h1 / h2 / h3
  CsrE*  csr  =(CsrE*)(ws+cur);  cur+=(size_t)EDGES*8;   // 8 MB raw CSR
  int*   chunkcnt=(int*)(ws+cur); cur+=2097152;          // 8 x 65536 ints
  float* chunkw  =(float*)(ws+cur); cur+=2097152;        // 8 x 65536 floats
  int*   rowptr=(int*) (ws+cur); cur+=262400;
  float* dinv1=(float*)(ws+cur); cur+=262144;
  float* dinv2=(float*)(ws+cur); cur+=131072;
  float* dinv3=(float*)(ws+cur); cur+=65536;
  float* sc1  =(float*)(ws+cur); cur+=262144;
  float* sc2  =(float*)(ws+cur); cur+=131072;
  float* sc3  =(float*)(ws+cur); cur+=65536;
  int*   inv1 =(int*)  (ws+cur); cur+=262144;
  int*   inv2 =(int*)  (ws+cur); cur+=131072;
  int*   invS =(int*)  (ws+cur); cur+=65536;
  int*   inv12=(int*)  (ws+cur); cur+=262144;
  int*   sel1 =(int*)  (ws+cur); cur+=131072;
  int*   sel2 =(int*)  (ws+cur); cur+=65536;
  int*   sel3 =(int*)  (ws+cur); cur+=32768;
  int*   map12=(int*)  (ws+cur); cur+=65536;
  int*   gcnt =(int*)  (ws+cur); cur+=256;               // tail counters (zeroed by cntpack)
  unsigned* wpk=(unsigned*)(ws+cur); cur+=196608;        // 3 x 64 KB packed W

  if (ws_size < cur) {
    k_zerof<<<(out_size+255)/256,256,0,stream>>>(out,out_size);
    return;
  }

  const int* esrc=ei; const int* edst=ei+EDGES;

  // ---------------- stage 1: 65536 nodes, K=512/graph ----------------
  // launch 1: CSR count (512 blocks) || W prepack (24 blocks) || gcnt zero
  k_cntpack<<<536,256,0,stream>>>(edst,ew,chunkcnt,chunkw,W1,W2,W3,wpk,gcnt);
  // launch 2: stage-1 matmul (512 blocks) || CSR scan+scatter (512 blocks)
  k_mm1scat<<<1024,256,0,stream>>>(x,wpk,esrc,edst,ew,chunkcnt,chunkw,
                                   rowptr,dinv1,csr,slot0);
  // launch 3: gather1 + tail-fused topk1 (last finisher of each graph's 128 blocks)
  k_gather<false,true><<<NTOT/8,256,0,stream>>>(slot0,csr,rowptr,nullptr,nullptr,
                                           dinv1,b1,p1,slot1,sc1,7,NTOT,
                                           gcnt,inv1,sel1);

  // ---------------- stage 2: 32768 nodes (space1), K=256 ----------------
  // mm2 (512 blocks) || degrow2 epilogue (128 blocks; consumer is gather2)
  mm_mfma<true,1,2,512><<<640,256,0,stream>>>(slot1,wpk+16384,sel1,sc1,slot0,3,
      inv1,sel1,nullptr,nullptr,nullptr,nullptr,rowptr,csr,dinv2);
  k_gather<true,false><<<32768/8,256,0,stream>>>(slot0,csr,rowptr,sel1,inv1,
                                           dinv2,b2,p2,slot1,sc2,6,32768,
                                           nullptr,nullptr,nullptr);
  k_topk<512,256,0><<<NB,512,0,stream>>>(sc2,inv2,sel2,nullptr,nullptr,nullptr,nullptr);

  // ---------------- stage 3: 16384 nodes (space2), K=128 ----------------
  // mm3 (256 blocks) || compose+degrow3 epilogue (64 graph-blocks)
  mm_mfma<true,1,3,256><<<320,256,0,stream>>>(slot1,wpk+32768,sel2,sc2,slot0,2,
      inv1,sel1,inv2,sel2,inv12,map12,rowptr,csr,dinv3);
  k_gather<true,false><<<16384/8,256,0,stream>>>(slot0,csr,rowptr,map12,inv12,
                                           dinv3,b3,p3,slot1,sc3,5,16384,
                                           nullptr,nullptr,nullptr);
  // topk3 + readout fused (MODE 3)
  k_topk<256,128,3><<<NB,256,0,stream>>>(sc3,invS,sel3,slot1,Wo,bo,out);
}

// Round 17
// 255.204 us; speedup vs baseline: 3.8794x; 3.8794x over previous
//
#include <hip/hip_runtime.h>

#define NB 64
#define EDGES 1048576   /* 64*1024*16 */
#define NTOT  65536

struct __align__(8) CsrE { int s; float w; };

using bf16x8 = __attribute__((ext_vector_type(8))) short;   // 8 bf16 (4 VGPRs)
using f32x4  = __attribute__((ext_vector_type(4))) float;   // 4 fp32 acc

__global__ void k_zerof(float* __restrict__ p, int n){
  int i=blockIdx.x*256+threadIdx.x; if(i<n) p[i]=0.f;
}

// ---------------- bf16x3 split helpers (RNE) ----------------
__device__ inline void split1(float x, unsigned &hi16, unsigned &lo16){
  unsigned b=__float_as_uint(x);
  unsigned h=(b+0x7FFFu+((b>>16)&1u))&0xFFFF0000u;
  float lf=x-__uint_as_float(h);
  unsigned lb=__float_as_uint(lf);
  hi16=h>>16;
  lo16=(lb+0x7FFFu+((lb>>16)&1u))>>16;
}

__device__ inline void split8(const float4&u, const float4&v, bf16x8&hi, bf16x8&lo){
  float e[8]={u.x,u.y,u.z,u.w,v.x,v.y,v.z,v.w};
  #pragma unroll
  for(int j=0;j<8;++j){
    unsigned h16,l16; split1(e[j],h16,l16);
    hi[j]=(short)h16; lo[j]=(short)l16;
  }
}

// Merged launch: blocks [0,512) = CSR count (8 chunks x 64 graphs, XCD-pinned,
// LDS histogram of 2048 edges); blocks [512,536) = W prepack (3 matrices into
// MFMA B-fragment order, bf16 hi/lo).
// Pack layout (u32): off(q,c,hl,l,i) = (((q*8+c)*2+hl)*64+l)*4+i
//   B[k][n]: k = 32q + 8*(l>>4) + j, n = 16c + (l&15); elem j=2i(lo),2i+1(hi).
__global__ __launch_bounds__(256) void k_cntpack(const int* __restrict__ edst,
        const float* __restrict__ ew, int* __restrict__ chunkcnt, float* __restrict__ chunkw,
        const float* __restrict__ W1, const float* __restrict__ W2,
        const float* __restrict__ W3, unsigned* __restrict__ outp){
  __shared__ int lc[1024];
  __shared__ float lw[1024];
  int b=blockIdx.x, tid=threadIdx.x;
  if(b<512){
    int xcd=b&7, slot=b>>3;
    int graph=xcd*8+(slot&7), chunk=slot>>3;     // chunk in [0,8)
    int e0=graph*16384+chunk*2048;
    for(int t=tid;t<1024;t+=256){ lc[t]=0; lw[t]=0.f; }
    __syncthreads();
    for(int e=e0+tid; e<e0+2048; e+=256){
      int dl=edst[e]&1023;
      atomicAdd(&lc[dl],1);
      atomicAdd(&lw[dl],ew[e]);
    }
    __syncthreads();
    for(int t=tid;t<1024;t+=256){
      chunkcnt[chunk*65536+graph*1024+t]=lc[t];
      chunkw  [chunk*65536+graph*1024+t]=lw[t];
    }
  } else {
    int wb=b-512, m=wb>>3;
    const float* W = (m==0)?W1:((m==1)?W2:W3);
    unsigned* o = outp + m*16384;
    for(int t=(wb&7)*256+tid; t<8192; t+=2048){
      int i=t&3, l=(t>>2)&63, c=(t>>8)&7, q=(t>>11)&3;
      int col=c*16+(l&15);
      int k0=q*32+((l>>4)<<3)+i*2;
      float x0=W[k0*128+col], x1=W[(k0+1)*128+col];
      unsigned h0,l0,h1,l1;
      split1(x0,h0,l0); split1(x1,h1,l1);
      int base=((q*8+c)*2)*256;           // u32 index of (q,c,hl=0)
      o[base + l*4 + i]       = (h1<<16)|h0;
      o[base + 256 + l*4 + i] = (l1<<16)|l0;
    }
  }
}

// Merged launch 2: blocks [0,512) = stage-1 MFMA matmul (128 rows each);
// blocks [512,1024) = CSR scatter w/ fused per-graph scan.
// LDS = 32 KB (W staged in two halves, q={0,1} then q={2,3}) -> 5 blocks/CU
// (was 64 KB -> 2 blocks/CU, Occupancy 18% latency-bound per r13 counters).
__global__ __launch_bounds__(256) void k_mm1scat(const float* __restrict__ X,
        const unsigned* __restrict__ Wpk,
        const int* __restrict__ esrc, const int* __restrict__ edst,
        const float* __restrict__ ew, const int* __restrict__ chunkcnt,
        const float* __restrict__ chunkw, int* __restrict__ rowptr,
        float* __restrict__ dinv1, CsrE* __restrict__ csr,
        float* __restrict__ Y){
  __shared__ __align__(16) unsigned Wl[8192];   // 32 KB (mm role); scatter aliases
  int b=blockIdx.x;
  if(b<512){
    const int RPB=128;
    int row0b=b*RPB;
    const int wave=threadIdx.x>>6, lane=threadIdx.x&63;
    const int row0=row0b+wave*32;
    const int lrow=lane&15, lko=(lane>>4)<<3;
    int orow[2];
    #pragma unroll
    for(int s=0;s<2;++s) orow[s]=row0+s*16+lrow;
    const f32x4 vzero={0.f,0.f,0.f,0.f};
    f32x4 acc[2][8];
    #pragma unroll
    for(int s=0;s<2;++s){
      #pragma unroll
      for(int c=0;c<8;++c) acc[s][c]=vzero;
    }
    const char* wb=(const char*)Wl + lane*16;
    float4 u[2],v[2];
    #pragma unroll
    for(int s=0;s<2;++s){
      const float* xp=X+(size_t)orow[s]*128+lko;
      u[s]=*(const float4*)xp; v[s]=*(const float4*)(xp+4);
    }
    #pragma unroll
    for(int p=0;p<2;++p){
      if(p) __syncthreads();             // all waves done reading half p-1
      for(int t=threadIdx.x;t<2048;t+=256)
        ((uint4*)Wl)[t]=((const uint4*)Wpk)[p*2048+t];
      __syncthreads();
      #pragma unroll
      for(int q2=0;q2<2;++q2){
        int q=p*2+q2;
        float4 un[2],vn[2];
        if(q<3){
          #pragma unroll
          for(int s=0;s<2;++s){
            const float* xp=X+(size_t)orow[s]*128+(q+1)*32+lko;
            un[s]=*(const float4*)xp; vn[s]=*(const float4*)(xp+4);
          }
        }
        bf16x8 Ah[2],Al[2];
        #pragma unroll
        for(int s=0;s<2;++s) split8(u[s],v[s],Ah[s],Al[s]);
        #pragma unroll
        for(int c=0;c<8;++c){
          const bf16x8 bh=*(const bf16x8*)(wb + (q2*8+c)*2048);
          const bf16x8 bl=*(const bf16x8*)(wb + (q2*8+c)*2048 + 1024);
          #pragma unroll
          for(int s=0;s<2;++s){
            acc[s][c]=__builtin_amdgcn_mfma_f32_16x16x32_bf16(Ah[s],bh,acc[s][c],0,0,0);
            acc[s][c]=__builtin_amdgcn_mfma_f32_16x16x32_bf16(Al[s],bh,acc[s][c],0,0,0);
            acc[s][c]=__builtin_amdgcn_mfma_f32_16x16x32_bf16(Ah[s],bl,acc[s][c],0,0,0);
          }
        }
        if(q<3){
          #pragma unroll
          for(int s=0;s<2;++s){ u[s]=un[s]; v[s]=vn[s]; }
        }
      }
    }
    const int dcol=lane&15, dr0=(lane>>4)<<2;
    #pragma unroll
    for(int s=0;s<2;++s){
      #pragma unroll
      for(int c=0;c<8;++c){
        #pragma unroll
        for(int r=0;r<4;++r){
          Y[(size_t)(row0+s*16+dr0+r)*128 + c*16 + dcol]=acc[s][c][r];
        }
      }
    }
  } else {
    int* lc=(int*)Wl;            // [0,1024) fill counters
    int* wsum=(int*)Wl+1024;     // wave partials
    int sb=b-512, i=threadIdx.x;
    int lane=i&63, w=i>>6;
    int xcd=sb&7, slot=sb>>3;
    int graph=xcd*8+(slot&7), chunk=slot>>3;    // chunk in [0,8)
    int n0=4*i, o0=graph*1024+n0;
    int ck[4][8], csum[4];
    int tot=0;
    #pragma unroll
    for(int j=0;j<4;++j){
      int c=0;
      #pragma unroll
      for(int k=0;k<8;++k){ int t=chunkcnt[k*65536+o0+j]; ck[j][k]=t; c+=t; }
      csum[j]=c; tot+=c;
    }
    int v=tot;
    #pragma unroll
    for(int off=1;off<64;off<<=1){ int t=__shfl_up(v,off,64); if(lane>=off) v+=t; }
    if(lane==63) wsum[w]=v;
    __syncthreads();
    int base=0;
    for(int k=0;k<w;++k) base+=wsum[k];
    int texcl=base+v-tot;
    int run=texcl;
    #pragma unroll
    for(int j=0;j<4;++j){
      int r0=graph*16384+run;
      if(chunk==0){
        rowptr[o0+j]=r0;
        float wsv=0.f;
        #pragma unroll
        for(int k=0;k<8;++k) wsv+=chunkw[k*65536+o0+j];
        dinv1[o0+j]=rsqrtf(wsv+1.0f);
      }
      int myfill=r0;
      #pragma unroll
      for(int k=0;k<8;++k) if(k<chunk) myfill+=ck[j][k];
      lc[n0+j]=myfill;
      run+=csum[j];
    }
    if(graph==63 && chunk==0 && i==255) rowptr[65536]=EDGES;
    __syncthreads();
    int e0=graph*16384+chunk*2048;
    for(int e=e0+i; e<e0+2048; e+=256){
      int dl=edst[e]&1023;
      int pos=atomicAdd(&lc[dl],1);
      CsrE ce; ce.s=esrc[e]; ce.w=ew[e];
      csr[pos]=ce;
    }
  }
}

// Y[R x 128] = act(A)[R x 128] @ W[128 x 128] via mfma_f32_16x16x32_bf16.
// LDS = 32 KB (two-half W staging) -> 5 blocks/CU. First MMB blocks do the
// matmul; extra blocks run a fused epilogue:
//   EPI=2: degrow2. EPI=3: compose (inv12,map12) + degrow3.
template<bool G, int S, int EPI, int MMB>
__global__ __launch_bounds__(256) void mm_mfma(const float* __restrict__ X,
        const unsigned* __restrict__ Wpk, const int* __restrict__ selold,
        const float* __restrict__ score, float* __restrict__ Y, int gshift,
        const int* __restrict__ inv1, const int* __restrict__ sel1,
        const int* __restrict__ inv2, const int* __restrict__ sel2,
        int* __restrict__ inv12, int* __restrict__ map12,
        const int* __restrict__ rowptr, const CsrE* __restrict__ csr,
        float* __restrict__ dinv_out){
  __shared__ __align__(16) unsigned Wl[8192];   // 32 KB
  int b=blockIdx.x;
  if(b<MMB){
    const int RPB = 64*S;
    int row0b;
    if(G){
      int xcd=b&7, slot=b>>3, bpg=1<<gshift;
      int graph=xcd*8+(slot>>gshift), idx=slot&(bpg-1);
      row0b = graph*(bpg*RPB) + idx*RPB;
    } else row0b = b*RPB;
    const int wave=threadIdx.x>>6, lane=threadIdx.x&63;
    const int row0 = row0b + wave*(16*S);
    const int lrow=lane&15, lko=(lane>>4)<<3;
    int orow[S]; float scr[S];
    #pragma unroll
    for(int s=0;s<S;++s){
      int rr=row0+s*16+lrow;
      orow[s]=G?selold[rr]:rr;
      scr[s]=G?score[orow[s]]:1.f;
    }
    const f32x4 vzero={0.f,0.f,0.f,0.f};
    f32x4 acc[S][8];
    #pragma unroll
    for(int s=0;s<S;++s){
      #pragma unroll
      for(int c=0;c<8;++c) acc[s][c]=vzero;
    }
    const char* wb=(const char*)Wl + lane*16;
    float4 u[S],v[S];
    #pragma unroll
    for(int s=0;s<S;++s){
      const float* xp=X+(size_t)orow[s]*128+lko;
      u[s]=*(const float4*)xp; v[s]=*(const float4*)(xp+4);
    }
    #pragma unroll
    for(int p=0;p<2;++p){
      if(p) __syncthreads();             // all waves done reading half p-1
      for(int t=threadIdx.x;t<2048;t+=256)
        ((uint4*)Wl)[t]=((const uint4*)Wpk)[p*2048+t];
      __syncthreads();
      #pragma unroll
      for(int q2=0;q2<2;++q2){
        int q=p*2+q2;
        float4 un[S],vn[S];
        if(q<3){
          #pragma unroll
          for(int s=0;s<S;++s){
            const float* xp=X+(size_t)orow[s]*128+(q+1)*32+lko;
            un[s]=*(const float4*)xp; vn[s]=*(const float4*)(xp+4);
          }
        }
        bf16x8 Ah[S],Al[S];
        #pragma unroll
        for(int s=0;s<S;++s){
          if(G){
            u[s].x=fmaxf(u[s].x*scr[s],0.f); u[s].y=fmaxf(u[s].y*scr[s],0.f);
            u[s].z=fmaxf(u[s].z*scr[s],0.f); u[s].w=fmaxf(u[s].w*scr[s],0.f);
            v[s].x=fmaxf(v[s].x*scr[s],0.f); v[s].y=fmaxf(v[s].y*scr[s],0.f);
            v[s].z=fmaxf(v[s].z*scr[s],0.f); v[s].w=fmaxf(v[s].w*scr[s],0.f);
          }
          split8(u[s],v[s],Ah[s],Al[s]);
        }
        #pragma unroll
        for(int c=0;c<8;++c){
          const bf16x8 bh=*(const bf16x8*)(wb + (q2*8+c)*2048);
          const bf16x8 bl=*(const bf16x8*)(wb + (q2*8+c)*2048 + 1024);
          #pragma unroll
          for(int s=0;s<S;++s){
            acc[s][c]=__builtin_amdgcn_mfma_f32_16x16x32_bf16(Ah[s],bh,acc[s][c],0,0,0);
            acc[s][c]=__builtin_amdgcn_mfma_f32_16x16x32_bf16(Al[s],bh,acc[s][c],0,0,0);
            acc[s][c]=__builtin_amdgcn_mfma_f32_16x16x32_bf16(Ah[s],bl,acc[s][c],0,0,0);
          }
        }
        if(q<3){
          #pragma unroll
          for(int s=0;s<S;++s){ u[s]=un[s]; v[s]=vn[s]; }
        }
      }
    }
    const int dcol=lane&15, dr0=(lane>>4)<<2;
    #pragma unroll
    for(int s=0;s<S;++s){
      #pragma unroll
      for(int c=0;c<8;++c){
        #pragma unroll
        for(int r=0;r<4;++r){
          Y[(size_t)(row0+s*16+dr0+r)*128 + c*16 + dcol]=acc[s][c][r];
        }
      }
    }
    return;
  }
  if(EPI==2){
    int v=(b-MMB)*256+threadIdx.x;        // [0, 32768)
    int d0=sel1[v];
    int rs=rowptr[d0], re=rowptr[d0+1];
    float s0=0.f,s1=0.f,s2=0.f,s3=0.f;
    int e=rs;
    for(; e+4<=re; e+=4){
      CsrE e0=csr[e], e1=csr[e+1], e2=csr[e+2], e3=csr[e+3];
      if(inv1[e0.s]>=0) s0+=e0.w;
      if(inv1[e1.s]>=0) s1+=e1.w;
      if(inv1[e2.s]>=0) s2+=e2.w;
      if(inv1[e3.s]>=0) s3+=e3.w;
    }
    for(; e<re; ++e){
      CsrE en=csr[e];
      if(inv1[en.s]>=0) s0+=en.w;
    }
    dinv_out[v]=rsqrtf((s0+s1)+(s2+s3)+1.0f);
  }
  if(EPI==3){
    int g=b-MMB, i=threadIdx.x;
    for(int t=i; t<1024; t+=256){
      int v0=g*1024+t;
      int q=inv1[v0];
      inv12[v0]=(q>=0)?inv2[q]:-1;
    }
    int v=g*256+i;
    map12[v]=sel1[sel2[v]];
    __syncthreads();   // inv12/map12 (this graph) visible in-block
    int d0=map12[v];
    int rs=rowptr[d0], re=rowptr[d0+1];
    float s0=0.f,s1=0.f,s2=0.f,s3=0.f;
    int e=rs;
    for(; e+4<=re; e+=4){
      CsrE e0=csr[e], e1=csr[e+1], e2=csr[e+2], e3=csr[e+3];
      if(inv12[e0.s]>=0) s0+=e0.w;
      if(inv12[e1.s]>=0) s1+=e1.w;
      if(inv12[e2.s]>=0) s2+=e2.w;
      if(inv12[e3.s]>=0) s3+=e3.w;
    }
    for(; e<re; ++e){
      CsrE en=csr[e];
      if(inv12[en.s]>=0) s0+=en.w;
    }
    dinv_out[v]=rsqrtf((s0+s1)+(s2+s3)+1.0f);
  }
}

// 2 nodes per wave (half-wave of 32 lanes each). XCD-swizzled. Branch-free
// 4-edge groups via width-32 shfl broadcast; dead/pad edges carry coef 0.
// Fused score (width-32 reduce).
template<bool F>
__global__ __launch_bounds__(256) void k_gather(const float* __restrict__ xw, const CsrE* __restrict__ csr,
        const int* __restrict__ rowptr, const int* __restrict__ map, const int* __restrict__ inv,
        const float* __restrict__ dinvv, const float* __restrict__ bias, const float* __restrict__ p,
        float* __restrict__ h, float* __restrict__ score, int gshift, int ns){
  int wv=threadIdx.x>>6, half=(threadIdx.x>>5)&1, hl=threadIdx.x&31;
  int b=blockIdx.x, xcd=b&7, slot=b>>3, bpg=1<<gshift;
  int graph=xcd*8+(slot>>gshift), idx=slot&(bpg-1);
  int v = graph*(bpg<<3) + (idx<<3) + wv*2 + half;   // 8 nodes per block
  if(v>=ns) return;
  int d0 = F? map[v] : v;
  float dv=dinvv[v];
  int rs=rowptr[d0], re=rowptr[d0+1];
  const int f4=hl*4;
  float4 accA={0.f,0.f,0.f,0.f}, accB={0.f,0.f,0.f,0.f};
  for(int base=rs; base<re; base+=32){
    int len=re-base; if(len>32) len=32;
    int sidx=0; float cf=0.f;
    if(hl<len){
      CsrE en=csr[base+hl];
      int s=en.s; bool live=true;
      if(F){ int t=inv[s]; live=(t>=0); s=live?t:0; }
      if(live){ sidx=s; cf=dinvv[s]*en.w; }
    }
    int len4=(len+3)&~3;
    for(int j=0;j<len4;j+=4){
      float c0=__shfl(cf,j,32),   c1=__shfl(cf,j+1,32);
      float c2=__shfl(cf,j+2,32), c3=__shfl(cf,j+3,32);
      int   s0=__shfl(sidx,j,32),   s1=__shfl(sidx,j+1,32);
      int   s2=__shfl(sidx,j+2,32), s3=__shfl(sidx,j+3,32);
      const float4 x0=*(const float4*)&xw[(size_t)s0*128+f4];
      const float4 x1=*(const float4*)&xw[(size_t)s1*128+f4];
      const float4 x2=*(const float4*)&xw[(size_t)s2*128+f4];
      const float4 x3=*(const float4*)&xw[(size_t)s3*128+f4];
      accA.x+=c0*x0.x; accA.y+=c0*x0.y; accA.z+=c0*x0.z; accA.w+=c0*x0.w;
      accB.x+=c1*x1.x; accB.y+=c1*x1.y; accB.z+=c1*x1.z; accB.w+=c1*x1.w;
      accA.x+=c2*x2.x; accA.y+=c2*x2.y; accA.z+=c2*x2.z; accA.w+=c2*x2.w;
      accB.x+=c3*x3.x; accB.y+=c3*x3.y; accB.z+=c3*x3.z; accB.w+=c3*x3.w;
    }
  }
  float4 acc; acc.x=accA.x+accB.x; acc.y=accA.y+accB.y;
  acc.z=accA.z+accB.z; acc.w=accA.w+accB.w;
  const float4 xv=*(const float4*)&xw[(size_t)v*128+f4];
  const float4 bv=*(const float4*)&bias[f4];
  float d2=dv*dv;
  float4 hv;
  hv.x=acc.x*dv + d2*xv.x + bv.x;
  hv.y=acc.y*dv + d2*xv.y + bv.y;
  hv.z=acc.z*dv + d2*xv.z + bv.z;
  hv.w=acc.w*dv + d2*xv.w + bv.w;
  *(float4*)&h[(size_t)v*128+f4]=hv;
  const float4 pv=*(const float4*)&p[f4];
  float z=hv.x*pv.x+hv.y*pv.y+hv.z*pv.z+hv.w*pv.w;
  float pp=pv.x*pv.x+pv.y*pv.y+pv.z*pv.z+pv.w*pv.w;
  #pragma unroll
  for(int m=16;m>0;m>>=1){ z+=__shfl_xor(z,m,32); pp+=__shfl_xor(pp,m,32); }
  if(hl==0) score[v]=1.0f/(1.0f+expf(-z/sqrtf(pp)));
}

// per-graph top-K via 4-pass MSB radix select. MODE 0: pure select.
// MODE 3: fused readout.
template<int N, int K, int MODE>
__global__ __launch_bounds__(N) void k_topk(const float* __restrict__ score,
        int* __restrict__ inv, int* __restrict__ selold,
        const float* __restrict__ h3, const float* __restrict__ Wo,
        const float* __restrict__ bo, float* __restrict__ outp){
  __shared__ unsigned hist[256];
  __shared__ int wsum[16];
  __shared__ int c_sh, r_sh;
  __shared__ float red[128];
  int g=blockIdx.x, i=threadIdx.x;
  int lane=i&63, w=i>>6;
  int gv=g*N+i;
  unsigned key=__float_as_uint(score[gv]);
  int st=1;              // 0=rejected, 1=alive, 2=selected
  int R=K;
  #pragma unroll
  for(int pass=0; pass<4; ++pass){
    int shift=24-pass*8;
    if(i<256) hist[i]=0;
    __syncthreads();
    unsigned byte=(key>>shift)&255u;
    if(st==1) atomicAdd(&hist[byte],1u);
    __syncthreads();
    unsigned hcnt=0, sfx=0;
    if(i<256){
      hcnt=hist[i]; sfx=hcnt;
      #pragma unroll
      for(int off=1;off<64;off<<=1){
        unsigned t=__shfl_down(sfx,off,64);
        if(lane+off<64) sfx+=t;
      }
      if(lane==0) wsum[w]=(int)sfx;
    }
    __syncthreads();
    if(i<256){
      int tot=0;
      for(int k=w+1;k<4;++k) tot+=wsum[k];
      int Si=(int)sfx+tot;
      int A=Si-(int)hcnt;
      if(A<R && R<=Si){ c_sh=i; r_sh=R-A; }
    }
    __syncthreads();
    int c=c_sh; R=r_sh;
    if(st==1){
      if((int)byte>c) st=2;
      else if((int)byte<c) st=0;
    }
    __syncthreads();
  }
  int alive=(st==1)?1:0;
  unsigned long long mA=__ballot(alive);
  int rA=__popcll(mA & ((1ULL<<lane)-1ULL));
  if(lane==0) wsum[w]=__popcll(mA);
  __syncthreads();
  int offA=0;
  for(int k=0;k<w;++k) offA+=wsum[k];
  int tie_rank=offA+rA;
  int sel=(st==2)||(st==1 && tie_rank<R);
  __syncthreads();
  unsigned long long mS=__ballot(sel);
  int rS=__popcll(mS & ((1ULL<<lane)-1ULL));
  if(lane==0) wsum[w]=__popcll(mS);
  __syncthreads();
  int offS=0;
  for(int k=0;k<w;++k) offS+=wsum[k];
  int ng=g*K+offS+rS;
  if(sel && ng<NB*K){ inv[gv]=ng; selold[ng]=gv; }
  else inv[gv]=-1;
  if(MODE==3){
    __syncthreads();   // selold (sel3) visible to the whole block
    int f=i;
    float mx=-3.4e38f, sm=0.f;
    if(f<128){
      for(int nd=0;nd<128;++nd){
        int old=selold[g*128+nd];
        float vv=fmaxf(h3[(size_t)old*128+f]*score[old],0.f);
        mx=fmaxf(mx,vv); sm+=vv;
      }
      float mean=sm*(1.0f/128.0f);
      outp[64+g*256+f]    =mx;
      outp[64+g*256+128+f]=mean;
      red[f]=mx*Wo[f]+mean*Wo[128+f];
    }
    __syncthreads();
    for(int off=64;off>0;off>>=1){
      if(f<off) red[f]+=red[f+off];
      __syncthreads();
    }
    if(f==0){ float z=red[0]+bo[0]; outp[g]=1.0f/(1.0f+expf(-z)); }
  }
}

extern "C" void kernel_launch(void* const* d_in, const int* in_sizes, int n_in,
                              void* d_out, int out_size, void* d_ws, size_t ws_size,
                              hipStream_t stream) {
  (void)in_sizes; (void)n_in;
  const float* x  = (const float*)d_in[0];
  const int*   ei = (const int*)d_in[1];
  const float* ew = (const float*)d_in[2];
  // d_in[3] = batch_index (unused; graphs are equal-sized)
  const float* W1=(const float*)d_in[4];  const float* b1=(const float*)d_in[5];  const float* p1=(const float*)d_in[6];
  const float* W2=(const float*)d_in[7];  const float* b2=(const float*)d_in[8];  const float* p2=(const float*)d_in[9];
  const float* W3=(const float*)d_in[10]; const float* b3=(const float*)d_in[11]; const float* p3=(const float*)d_in[12];
  const float* Wo=(const float*)d_in[13]; const float* bo=(const float*)d_in[14];
  float* out=(float*)d_out;

  // ---- workspace layout (~81 MiB) ----
  char* ws=(char*)d_ws;
  size_t cur=0;
  float* slot0=(float*)(ws+cur); cur+=33554432;          // xw1 / xw2 / xw3
  float* slot1=(float*)(ws+cur); cur+=33554432;          // h1 / h2 / h3
  CsrE*  csr  =(CsrE*)(ws+cur);  cur+=(size_t)EDGES*8;   // 8 MB raw CSR
  int*   chunkcnt=(int*)(ws+cur); cur+=2097152;          // 8 x 65536 ints
  float* chunkw  =(float*)(ws+cur); cur+=2097152;        // 8 x 65536 floats
  int*   rowptr=(int*) (ws+cur); cur+=262400;
  float* dinv1=(float*)(ws+cur); cur+=262144;
  float* dinv2=(float*)(ws+cur); cur+=131072;
  float* dinv3=(float*)(ws+cur); cur+=65536;
  float* sc1  =(float*)(ws+cur); cur+=262144;
  float* sc2  =(float*)(ws+cur); cur+=131072;
  float* sc3  =(float*)(ws+cur); cur+=65536;
  int*   inv1 =(int*)  (ws+cur); cur+=262144;
  int*   inv2 =(int*)  (ws+cur); cur+=131072;
  int*   invS =(int*)  (ws+cur); cur+=65536;
  int*   inv12=(int*)  (ws+cur); cur+=262144;
  int*   sel1 =(int*)  (ws+cur); cur+=131072;
  int*   sel2 =(int*)  (ws+cur); cur+=65536;
  int*   sel3 =(int*)  (ws+cur); cur+=32768;
  int*   map12=(int*)  (ws+cur); cur+=65536;
  unsigned* wpk=(unsigned*)(ws+cur); cur+=196608;        // 3 x 64 KB packed W

  if (ws_size < cur) {
    k_zerof<<<(out_size+255)/256,256,0,stream>>>(out,out_size);
    return;
  }

  const int* esrc=ei; const int* edst=ei+EDGES;

  // ---------------- stage 1: 65536 nodes, K=512/graph ----------------
  // launch 1: CSR count (512 blocks) || W prepack (24 blocks)
  k_cntpack<<<536,256,0,stream>>>(edst,ew,chunkcnt,chunkw,W1,W2,W3,wpk);
  // launch 2: stage-1 matmul (512 blocks) || CSR scan+scatter (512 blocks)
  k_mm1scat<<<1024,256,0,stream>>>(x,wpk,esrc,edst,ew,chunkcnt,chunkw,
                                   rowptr,dinv1,csr,slot0);
  k_gather<false><<<NTOT/8,256,0,stream>>>(slot0,csr,rowptr,nullptr,nullptr,
                                           dinv1,b1,p1,slot1,sc1,7,NTOT);
  k_topk<1024,512,0><<<NB,1024,0,stream>>>(sc1,inv1,sel1,nullptr,nullptr,nullptr,nullptr);

  // ---------------- stage 2: 32768 nodes (space1), K=256 ----------------
  // mm2 (512 blocks) || degrow2 epilogue (128 blocks; consumer is gather2)
  mm_mfma<true,1,2,512><<<640,256,0,stream>>>(slot1,wpk+16384,sel1,sc1,slot0,3,
      inv1,sel1,nullptr,nullptr,nullptr,nullptr,rowptr,csr,dinv2);
  k_gather<true><<<32768/8,256,0,stream>>>(slot0,csr,rowptr,sel1,inv1,
                                           dinv2,b2,p2,slot1,sc2,6,32768);
  k_topk<512,256,0><<<NB,512,0,stream>>>(sc2,inv2,sel2,nullptr,nullptr,nullptr,nullptr);

  // ---------------- stage 3: 16384 nodes (space2), K=128 ----------------
  // mm3 (256 blocks) || compose+degrow3 epilogue (64 graph-blocks)
  mm_mfma<true,1,3,256><<<320,256,0,stream>>>(slot1,wpk+32768,sel2,sc2,slot0,2,
      inv1,sel1,inv2,sel2,inv12,map12,rowptr,csr,dinv3);
  k_gather<true><<<16384/8,256,0,stream>>>(slot0,csr,rowptr,map12,inv12,
                                           dinv3,b3,p3,slot1,sc3,5,16384);
  // topk3 + readout fused (MODE 3)
  k_topk<256,128,3><<<NB,256,0,stream>>>(sc3,invS,sel3,slot1,Wo,bo,out);
}